// Round 10
// baseline (77.812 us; speedup 1.0000x reference)
//
#include <hip/hip_runtime.h>

// uvs [B=16, J=16, M=512, D=256] fp32. j<8 = u (k=j), j>=8 = v (k=j-8).
// gate_u[b,k,m] = (dot(u[b,k,m,:], colsum(v[b,k])) > 0); symmetric for v.
//
// R9 failure: 128 fat blocks = half the CUs idle (63 us). Fix: 256 blocks —
// one per (b,k,half): block (bk,s) owns rows [s*256, s*256+256) of u AND v.
// Its 256 v-rows live entirely in vreg[16] (AGPR-parked, proven R6-R9) so v
// is read from HBM exactly once. Only dependency: the PARTNER block (blk^1)
// — exchange 1 KiB colsum partials via ws with R7's proven fence-free
// protocol (relaxed agent-scope atomics, __syncthreads drains stores before
// the flag, monotonic flag 1->2, flags zeroed per launch by memsetAsync).
// vs/us are summed in fixed slot order in BOTH blocks -> bit-identical,
// replay-deterministic gates. Traffic: 134 MB read + 134 MB write = 268 MB,
// one dispatch, all 256 CUs.

#define NBLK 256
#define NTHR 1024

typedef float f32x4 __attribute__((ext_vector_type(4)));

__device__ __forceinline__ void part_store(float* p, f32x4 v) {
    __hip_atomic_store(p + 0, v.x, __ATOMIC_RELAXED, __HIP_MEMORY_SCOPE_AGENT);
    __hip_atomic_store(p + 1, v.y, __ATOMIC_RELAXED, __HIP_MEMORY_SCOPE_AGENT);
    __hip_atomic_store(p + 2, v.z, __ATOMIC_RELAXED, __HIP_MEMORY_SCOPE_AGENT);
    __hip_atomic_store(p + 3, v.w, __ATOMIC_RELAXED, __HIP_MEMORY_SCOPE_AGENT);
}
__device__ __forceinline__ f32x4 part_load(const float* p) {
    f32x4 r;
    r.x = __hip_atomic_load(p + 0, __ATOMIC_RELAXED, __HIP_MEMORY_SCOPE_AGENT);
    r.y = __hip_atomic_load(p + 1, __ATOMIC_RELAXED, __HIP_MEMORY_SCOPE_AGENT);
    r.z = __hip_atomic_load(p + 2, __ATOMIC_RELAXED, __HIP_MEMORY_SCOPE_AGENT);
    r.w = __hip_atomic_load(p + 3, __ATOMIC_RELAXED, __HIP_MEMORY_SCOPE_AGENT);
    return r;
}

__device__ __forceinline__ float row_gate(f32x4 v, f32x4 s) {
    float p = v.x * s.x + v.y * s.y + v.z * s.z + v.w * s.w;
#pragma unroll
    for (int off = 32; off; off >>= 1) p += __shfl_xor(p, off, 64);
    return (p > 0.f) ? 1.f : 0.f;
}

// 1024-thread column-sum tree -> 64 f32x4, stored to ws slot by t<64.
// Caller must __syncthreads() after (store drain) before flagging.
__device__ __forceinline__ void tree_to_ws(f32x4 acc, int t, f32x4* red,
                                           float* __restrict__ slot) {
    red[t] = acc;
    __syncthreads();
    if (t < 64) {
        f32x4 r = {0.f, 0.f, 0.f, 0.f};
#pragma unroll
        for (int q = 0; q < 16; ++q) r += red[q * 64 + t];
        part_store(slot + (size_t)t * 4, r);
    }
    __syncthreads();   // drains the part_store vmcnt before any flag store
}

__global__ __launch_bounds__(NTHR)
void k_pair(const f32x4* __restrict__ in,
            f32x4* __restrict__ out,
            float* __restrict__ vpart,      // [256][64][4] floats
            float* __restrict__ upart,      // [256][64][4] floats
            unsigned* __restrict__ flag) {  // [256], zeroed per launch
    const int blk = blockIdx.x;             // bk*2 + s
    const int s   = blk & 1;
    const int bk  = blk >> 1;               // [0,128)
    const int b   = bk >> 3, k = bk & 7;
    const int par = blk ^ 1;
    const int t   = threadIdx.x;
    const int l   = t & 63;
    const int w   = t >> 6;                 // [0,16)

    const size_t ubase = ((size_t)((b * 16 + k) * 512)     + s * 256 + w * 16) * 64 + l;
    const size_t vbase = ((size_t)((b * 16 + 8 + k) * 512) + s * 256 + w * 16) * 64 + l;

    __shared__ f32x4 red[NTHR];             // 16 KiB

    // ---- Phase A: own 256 v-rows -> vreg; partial colsum -> ws; flag=1 ----
    f32x4 vreg[16];
    f32x4 acc = {0.f, 0.f, 0.f, 0.f};
#pragma unroll
    for (int i = 0; i < 16; ++i) {
        vreg[i] = __builtin_nontemporal_load(in + vbase + (size_t)i * 64);
        acc += vreg[i];
    }
    tree_to_ws(acc, t, red, vpart + (size_t)blk * 256);
    if (t == 0)
        __hip_atomic_store(flag + blk, 1u, __ATOMIC_RELAXED, __HIP_MEMORY_SCOPE_AGENT);

    // ---- Rendezvous 1: wait partner's v-partial; vs = slot[2bk]+slot[2bk+1] ----
    if (t == 0) {
        while (__hip_atomic_load(flag + par, __ATOMIC_RELAXED, __HIP_MEMORY_SCOPE_AGENT) < 1u)
            __builtin_amdgcn_s_sleep(2);
    }
    __syncthreads();
    const f32x4 vs = part_load(vpart + (size_t)(bk * 2 + 0) * 256 + (size_t)l * 4) +
                     part_load(vpart + (size_t)(bk * 2 + 1) * 256 + (size_t)l * 4);

    // ---- Phase B: stream own 256 u-rows once; gate; usum partial; flag=2 ----
    f32x4 uacc = {0.f, 0.f, 0.f, 0.f};
#pragma unroll 4
    for (int i = 0; i < 16; ++i) {
        f32x4 uv = __builtin_nontemporal_load(in + ubase + (size_t)i * 64);
        uacc += uv;
        const float g = row_gate(uv, vs);
        __builtin_nontemporal_store(uv * g, out + ubase + (size_t)i * 64);
    }
    tree_to_ws(uacc, t, red, upart + (size_t)blk * 256);
    if (t == 0)
        __hip_atomic_store(flag + blk, 2u, __ATOMIC_RELAXED, __HIP_MEMORY_SCOPE_AGENT);

    // ---- Rendezvous 2: wait partner's u-partial; us = fixed-order sum ----
    if (t == 0) {
        while (__hip_atomic_load(flag + par, __ATOMIC_RELAXED, __HIP_MEMORY_SCOPE_AGENT) < 2u)
            __builtin_amdgcn_s_sleep(2);
    }
    __syncthreads();
    const f32x4 us = part_load(upart + (size_t)(bk * 2 + 0) * 256 + (size_t)l * 4) +
                     part_load(upart + (size_t)(bk * 2 + 1) * 256 + (size_t)l * 4);

    // ---- Phase C: gate register-resident v; NT store (no v re-read) ----
#pragma unroll
    for (int i = 0; i < 16; ++i) {
        const float g = row_gate(vreg[i], us);
        __builtin_nontemporal_store(vreg[i] * g, out + vbase + (size_t)i * 64);
    }
}

extern "C" void kernel_launch(void* const* d_in, const int* in_sizes, int n_in,
                              void* d_out, int out_size, void* d_ws, size_t ws_size,
                              hipStream_t stream) {
    const f32x4* in  = (const f32x4*)d_in[0];
    f32x4*       out = (f32x4*)d_out;
    // ws: vpart 256 KiB @ 0, upart 256 KiB @ 256 KiB (single-writer slots,
    // written before read each call), flags 1 KiB @ 512 KiB (zeroed below).
    float*    vpart = (float*)d_ws;
    float*    upart = (float*)((char*)d_ws + (256u << 10));
    unsigned* flag  = (unsigned*)((char*)d_ws + (512u << 10));

    hipMemsetAsync(flag, 0, NBLK * sizeof(unsigned), stream);  // replay-safe

    void* args[] = { (void*)&in, (void*)&out, (void*)&vpart, (void*)&upart, (void*)&flag };
    hipLaunchCooperativeKernel((void*)k_pair, dim3(NBLK), dim3(NTHR),
                               args, 0, stream);
}

// Round 11
// 59.589 us; speedup vs baseline: 1.3058x; 1.3058x over previous
//
#include <hip/hip_runtime.h>
#include <hip/hip_bf16.h>

// uvs [B=16, J=16, M=512, D=256] fp32. j<8 = u (k=j), j>=8 = v (k=j-8).
// gate_u[b,k,m] = (dot(u[b,k,m,:], colsum(v[b,k])) > 0); symmetric for v.
//
// FINAL STRUCTURE (R8, 59.9 us): 3-kernel multi-pass, 512-thr blocks
// (32 waves/CU). Nominal traffic 335 MB @ ~6.3 TB/s mixed-stream + 3 launch
// gaps = 59-60 us -> at the memory roofline for this structure.
// Fusion attempts R4-R7/R9/R10 (268 MB with on-chip v retention) all lost
// (63-133 us): the 9.6 us re-read saving < grid/pair-sync + occupancy costs.
//   K1: v -> vsum partials                      (read 67 MB)
//   K2: u -> gated-u + usum partials            (read 67, write 67)
//   K3: v re-read -> gated-v                    (read 67, write 67)
// Deterministic tree reductions via d_ws partials; no atomics (gate signs
// replay-stable).

#define B_   16
#define K_   8
#define M_   512
#define D4_  64          // 256 floats = 64 float4 per row
#define S_   8           // m-splits -> 1024 blocks per pass
#define NT_  512         // threads/block = 8 waves

typedef float f32x4 __attribute__((ext_vector_type(4)));

// Block-level column-sum reduce: 512 threads -> 64 lanes, then store.
__device__ __forceinline__ void block_colsum_store(f32x4 acc, int t,
                                                   f32x4* red,
                                                   f32x4* __restrict__ dst) {
    red[t] = acc;
    __syncthreads();
    if (t < 64) {
        f32x4 r = {0.f, 0.f, 0.f, 0.f};
#pragma unroll
        for (int q = 0; q < 8; ++q) r += red[q * 64 + t];
        dst[t] = r;
    }
}

// --------------------------------------------------------------------------
// K1: partial column sums of the v half. Grid 1024 = (b,k) x s.
// Block sums rows [s*64, s*64+64) of v[b,k]; wave w rows [w*8, w*8+8).
// --------------------------------------------------------------------------
__global__ __launch_bounds__(NT_) void k_vsum(const f32x4* __restrict__ in,
                                              f32x4* __restrict__ vpart) {
    const int blk = blockIdx.x;
    const int s   = blk & (S_ - 1);
    const int bk  = blk >> 3;                 // [0,128)
    const int b   = bk >> 3, k = bk & 7;
    const int t   = threadIdx.x;
    const int l   = t & 63;
    const int w   = t >> 6;                   // [0,8)

    const f32x4* base = in + ((size_t)((b * 16 + 8 + k) * M_) + s * 64 + w * 8) * D4_ + l;

    f32x4 acc = {0.f, 0.f, 0.f, 0.f};
#pragma unroll
    for (int i = 0; i < 8; ++i) acc += base[(size_t)i * D4_];

    __shared__ f32x4 red[NT_];
    block_colsum_store(acc, t, red, vpart + (size_t)blk * 64);
}

// --------------------------------------------------------------------------
// K2: u pass. Gather vsum (8 partials) -> registers; stream 64 rows of u:
// load -> dot -> 6-step shfl_xor wave reduce -> gate -> NT store gated u.
// Accumulate block-partial usum -> upart.
// --------------------------------------------------------------------------
__global__ __launch_bounds__(NT_) void k_upass(const f32x4* __restrict__ in,
                                               const f32x4* __restrict__ vpart,
                                               f32x4* __restrict__ upart,
                                               f32x4* __restrict__ out) {
    const int blk = blockIdx.x;
    const int s   = blk & (S_ - 1);
    const int bk  = blk >> 3;
    const int b   = bk >> 3, k = bk & 7;
    const int t   = threadIdx.x;
    const int l   = t & 63;
    const int w   = t >> 6;

    f32x4 vs = {0.f, 0.f, 0.f, 0.f};
#pragma unroll
    for (int q = 0; q < S_; ++q) vs += vpart[(size_t)(bk * S_ + q) * 64 + l];

    const size_t rowbase = ((size_t)((b * 16 + k) * M_) + s * 64 + w * 8) * D4_ + l;
    const f32x4* inb  = in + rowbase;
    f32x4*       outb = (f32x4*)(out + rowbase);

    f32x4 uacc = {0.f, 0.f, 0.f, 0.f};
#pragma unroll
    for (int i = 0; i < 8; ++i) {
        f32x4 uv = inb[(size_t)i * D4_];
        uacc += uv;
        float p = uv.x * vs.x + uv.y * vs.y + uv.z * vs.z + uv.w * vs.w;
#pragma unroll
        for (int off = 32; off; off >>= 1) p += __shfl_xor(p, off, 64);
        const float g = (p > 0.f) ? 1.f : 0.f;
        __builtin_nontemporal_store(uv * g, outb + (size_t)i * D4_);
    }

    __shared__ f32x4 red[NT_];
    block_colsum_store(uacc, t, red, upart + (size_t)blk * 64);
}

// --------------------------------------------------------------------------
// K3: v pass. Gather usum -> registers; re-read v, gate, NT store gated v.
// --------------------------------------------------------------------------
__global__ __launch_bounds__(NT_) void k_vpass(const f32x4* __restrict__ in,
                                               const f32x4* __restrict__ upart,
                                               f32x4* __restrict__ out) {
    const int blk = blockIdx.x;
    const int s   = blk & (S_ - 1);
    const int bk  = blk >> 3;
    const int b   = bk >> 3, k = bk & 7;
    const int t   = threadIdx.x;
    const int l   = t & 63;
    const int w   = t >> 6;

    f32x4 us = {0.f, 0.f, 0.f, 0.f};
#pragma unroll
    for (int q = 0; q < S_; ++q) us += upart[(size_t)(bk * S_ + q) * 64 + l];

    const size_t rowbase = ((size_t)((b * 16 + 8 + k) * M_) + s * 64 + w * 8) * D4_ + l;
    const f32x4* inb  = in + rowbase;
    f32x4*       outb = (f32x4*)(out + rowbase);

#pragma unroll
    for (int i = 0; i < 8; ++i) {
        f32x4 vv = inb[(size_t)i * D4_];
        float p = vv.x * us.x + vv.y * us.y + vv.z * us.z + vv.w * us.w;
#pragma unroll
        for (int off = 32; off; off >>= 1) p += __shfl_xor(p, off, 64);
        const float g = (p > 0.f) ? 1.f : 0.f;
        __builtin_nontemporal_store(vv * g, outb + (size_t)i * D4_);
    }
}

extern "C" void kernel_launch(void* const* d_in, const int* in_sizes, int n_in,
                              void* d_out, int out_size, void* d_ws, size_t ws_size,
                              hipStream_t stream) {
    const f32x4* in  = (const f32x4*)d_in[0];
    f32x4*       out = (f32x4*)d_out;
    // ws: vpart 1 MiB @ 0, upart 1 MiB @ 1 MiB.
    // Both fully written before read each call; no atomics anywhere.
    f32x4* vpart = (f32x4*)d_ws;
    f32x4* upart = (f32x4*)((char*)d_ws + (1u << 20));

    const int grid = B_ * K_ * S_;   // 1024
    k_vsum <<<grid, NT_, 0, stream>>>(in, vpart);
    k_upass<<<grid, NT_, 0, stream>>>(in, vpart, upart, out);
    k_vpass<<<grid, NT_, 0, stream>>>(in, upart, out);
}